// Round 1
// baseline (446.768 us; speedup 1.0000x reference)
//
#include <hip/hip_runtime.h>
#include <math.h>

#define KW 65
#define L_LEN 65536
#define B_N 32
#define OC_N 64
#define LT 1024
#define OCB 8

__device__ __forceinline__ float nan0(float v) {
    if (isnan(v)) return 0.0f;
    if (isinf(v)) return v > 0.0f ? 3.4028234663852886e38f : -3.4028234663852886e38f;
    return v;
}

// ---------------- Kernel A: build per-batch steered weights -----------------
// wout layout: [B][OC][2][KW] contiguous
__global__ __launch_bounds__(128) void steer_weights(
        const int* __restrict__ z, const float* __restrict__ s,
        const float* __restrict__ bw, float* __restrict__ wout) {
    const float PI = 3.14159265358979323846f;
    const float FS = 50000000.0f;
    int b = blockIdx.x;
    int t = threadIdx.x;

    const int*   zb = z + b * 5;
    const float* sb = s + b * 5;
    float f0    = (zb[0] > 0) ? nan0(sb[0]) : 0.0f;
    float alpha = (zb[1] > 0) ? nan0(sb[1]) : 1.0f;
    float gain  = (zb[2] > 0) ? nan0(sb[2]) : 1.0f;
    float shf   = (zb[3] > 0) ? nan0(sb[3]) : 0.0f;
    float chirp = (zb[4] > 0) ? nan0(sb[4]) : 0.0f;

    float a = fmaxf(alpha, 0.001f);
    float Nf_raw = rintf(65.0f / a);              // jnp.round = half-to-even = rintf
    int   N  = (int)fminf(fmaxf(Nf_raw, 1.0f), 130.0f);
    float Nf = (float)N;
    int   sh = (int)rintf(shf);

    __shared__ float rw[OC_N][2][KW];

    if (t < 128) {
        int oc = t >> 1, ch = t & 1;
        const float* w = bw + (oc * 2 + ch) * KW;
        float KdivN = 65.0f / Nf;
        float NdivK = Nf / 65.0f;
        for (int i = 0; i < KW; ++i) {
            float c2  = fmaxf(((float)i + 0.5f) * NdivK - 0.5f, 0.0f);
            float j0f = floorf(c2);
            int   j0  = (int)j0f;
            int   j1  = min(j0 + 1, N - 1);
            float w2  = c2 - j0f;
            float v0, v1;
            {
                float c   = fmaxf(((float)j0 + 0.5f) * KdivN - 0.5f, 0.0f);
                float i0f = floorf(c);
                int   i0  = min((int)i0f, KW - 1);
                int   i1  = min(i0 + 1, KW - 1);
                float w1  = c - i0f;
                v0 = (1.0f - w1) * w[i0] + w1 * w[i1];
            }
            {
                float c   = fmaxf(((float)j1 + 0.5f) * KdivN - 0.5f, 0.0f);
                float i0f = floorf(c);
                int   i0  = min((int)i0f, KW - 1);
                int   i1  = min(i0 + 1, KW - 1);
                float w1  = c - i0f;
                v1 = (1.0f - w1) * w[i0] + w1 * w[i1];
            }
            rw[oc][ch][i] = (1.0f - w2) * v0 + w2 * v1;
        }
    }
    __syncthreads();
    if (t < OC_N) {
        int oc = t;
        float* ob = wout + ((size_t)b * OC_N + oc) * 2 * KW;
        for (int k = 0; k < KW; ++k) {
            float n  = (float)k;
            float tt = n / FS;
            float phi = 2.0f * PI * f0 * n / FS + PI * chirp * tt * tt;
            float cph = cosf(phi), sph = sinf(phi);
            float I = rw[oc][0][k], Q = rw[oc][1][k];
            float Ip = (I * cph - Q * sph) * gain;
            float Qp = (I * sph + Q * cph) * gain;
            int kk = ((k + sh) % KW + KW) % KW;   // out[(k+sh)%KW] = in[k]
            ob[kk]      = Ip;
            ob[KW + kk] = Qp;
        }
    }
}

// ---------------- Kernel B: grouped 1-D conv ---------------------------------
__global__ __launch_bounds__(256) void steer_conv(
        const float* __restrict__ x, const float* __restrict__ wb,
        float* __restrict__ y) {
    int lt = blockIdx.x;     // 64 tiles of 1024
    int ob = blockIdx.y;     // 8 oc-blocks of 8
    int b  = blockIdx.z;     // 32 batches
    int l0 = lt * LT;
    int tid = threadIdx.x;

    __shared__ float xt[2][LT + 64 + 4];   // xt[ch][i] = x[b,ch, l0-32+i]
    __shared__ float wt[OCB][2][68];       // 68-float rows -> 16B aligned k4 reads

    const float* xb = x + (size_t)b * 2 * L_LEN;

    // stage x tile (zero-padded at array edges)
    for (int ch = 0; ch < 2; ++ch) {
        for (int v = tid; v < (LT + 64) / 4; v += 256) {
            int gi = l0 - 32 + v * 4;      // 4-aligned
            float4 val;
            if (gi >= 0 && gi + 3 < L_LEN) {
                val = *(const float4*)(xb + (size_t)ch * L_LEN + gi);
            } else {
                float tmp[4];
                #pragma unroll
                for (int u = 0; u < 4; ++u) {
                    int g = gi + u;
                    tmp[u] = (g >= 0 && g < L_LEN) ? xb[(size_t)ch * L_LEN + g] : 0.0f;
                }
                val = make_float4(tmp[0], tmp[1], tmp[2], tmp[3]);
            }
            *(float4*)&xt[ch][v * 4] = val;
        }
    }
    // stage weights for this (b, oc-block)
    for (int v = tid; v < OCB * 2 * KW; v += 256) {
        int oc = v / (2 * KW);
        int r  = v % (2 * KW);
        int ch = r / KW;
        int k  = r % KW;
        wt[oc][ch][k] = wb[(((size_t)b * OC_N + ob * OCB + oc) * 2 + ch) * KW + k];
    }
    __syncthreads();

    int base = tid * 4;                    // thread's 4 consecutive outputs
    float acc[OCB][4];
    #pragma unroll
    for (int oc = 0; oc < OCB; ++oc)
        #pragma unroll
        for (int j = 0; j < 4; ++j) acc[oc][j] = 0.0f;

    float4 cur0 = *(const float4*)&xt[0][base];
    float4 cur1 = *(const float4*)&xt[1][base];

    #pragma unroll 2
    for (int k4 = 0; k4 < 64; k4 += 4) {
        float4 nxt0 = *(const float4*)&xt[0][base + k4 + 4];
        float4 nxt1 = *(const float4*)&xt[1][base + k4 + 4];
        float win0[8] = {cur0.x, cur0.y, cur0.z, cur0.w, nxt0.x, nxt0.y, nxt0.z, nxt0.w};
        float win1[8] = {cur1.x, cur1.y, cur1.z, cur1.w, nxt1.x, nxt1.y, nxt1.z, nxt1.w};
        #pragma unroll
        for (int oc = 0; oc < OCB; ++oc) {
            float4 w0 = *(const float4*)&wt[oc][0][k4];
            float4 w1 = *(const float4*)&wt[oc][1][k4];
            float wa0[4] = {w0.x, w0.y, w0.z, w0.w};
            float wa1[4] = {w1.x, w1.y, w1.z, w1.w};
            #pragma unroll
            for (int kk = 0; kk < 4; ++kk)
                #pragma unroll
                for (int j = 0; j < 4; ++j) {
                    acc[oc][j] = fmaf(win0[kk + j], wa0[kk], acc[oc][j]);
                    acc[oc][j] = fmaf(win1[kk + j], wa1[kk], acc[oc][j]);
                }
        }
        cur0 = nxt0; cur1 = nxt1;
    }
    // tap k = 64: window regs cur = xt[][base+64 .. base+67]
    {
        float ca0[4] = {cur0.x, cur0.y, cur0.z, cur0.w};
        float ca1[4] = {cur1.x, cur1.y, cur1.z, cur1.w};
        #pragma unroll
        for (int oc = 0; oc < OCB; ++oc) {
            float w0 = wt[oc][0][64], w1 = wt[oc][1][64];
            #pragma unroll
            for (int j = 0; j < 4; ++j) {
                acc[oc][j] = fmaf(ca0[j], w0, acc[oc][j]);
                acc[oc][j] = fmaf(ca1[j], w1, acc[oc][j]);
            }
        }
    }

    #pragma unroll
    for (int oc = 0; oc < OCB; ++oc) {
        float4 o = make_float4(acc[oc][0], acc[oc][1], acc[oc][2], acc[oc][3]);
        *(float4*)&y[((size_t)b * OC_N + ob * OCB + oc) * L_LEN + l0 + base] = o;
    }
}

extern "C" void kernel_launch(void* const* d_in, const int* in_sizes, int n_in,
                              void* d_out, int out_size, void* d_ws, size_t ws_size,
                              hipStream_t stream) {
    const float* x  = (const float*)d_in[0];
    const int*   z  = (const int*)d_in[1];
    const float* s  = (const float*)d_in[2];
    const float* bw = (const float*)d_in[3];
    float* y      = (float*)d_out;
    float* wsteer = (float*)d_ws;   // needs 32*64*2*65*4 = 1.04 MB

    steer_weights<<<dim3(B_N), dim3(128), 0, stream>>>(z, s, bw, wsteer);
    steer_conv<<<dim3(L_LEN / LT, OC_N / OCB, B_N), dim3(256), 0, stream>>>(x, wsteer, y);
}

// Round 2
// 208.799 us; speedup vs baseline: 2.1397x; 2.1397x over previous
//
#include <hip/hip_runtime.h>
#include <math.h>

#define KW 65
#define L_LEN 65536
#define B_N 32
#define OC_N 64
#define KPAD 160      // two 80-wide channel sections
#define SEC 80
#define LT 128        // l per block
#define XW 208        // staged bf16 window per (phase, ch): i in [0,208)

typedef __attribute__((ext_vector_type(8))) short short8;
typedef __attribute__((ext_vector_type(4))) float f32x4;

__device__ __forceinline__ unsigned short f2bf(float f) {
    unsigned u = __builtin_bit_cast(unsigned, f);
    unsigned r = u + 0x7FFFu + ((u >> 16) & 1u);
    return (unsigned short)(r >> 16);
}

__device__ __forceinline__ float nan0(float v) {
    if (isnan(v)) return 0.0f;
    if (isinf(v)) return v > 0.0f ? 3.4028234663852886e38f : -3.4028234663852886e38f;
    return v;
}

// ---------------- Kernel A: steered weights, packed bf16 [B][OC][160] -------
// section 0: taps 0..64 of ch I at kk=0..64, pad 65..79 = 0
// section 1: taps 0..64 of ch Q at kk=80..144, pad 145..159 = 0
__global__ __launch_bounds__(128) void steer_weights(
        const int* __restrict__ z, const float* __restrict__ s,
        const float* __restrict__ bw, unsigned short* __restrict__ wpk) {
    const float PI = 3.14159265358979323846f;
    const float FS = 50000000.0f;
    int b = blockIdx.x;
    int t = threadIdx.x;

    const int*   zb = z + b * 5;
    const float* sb = s + b * 5;
    float f0    = (zb[0] > 0) ? nan0(sb[0]) : 0.0f;
    float alpha = (zb[1] > 0) ? nan0(sb[1]) : 1.0f;
    float gain  = (zb[2] > 0) ? nan0(sb[2]) : 1.0f;
    float shf   = (zb[3] > 0) ? nan0(sb[3]) : 0.0f;
    float chirp = (zb[4] > 0) ? nan0(sb[4]) : 0.0f;

    float a = fmaxf(alpha, 0.001f);
    float Nf_raw = rintf(65.0f / a);          // jnp.round = half-to-even
    int   N  = (int)fminf(fmaxf(Nf_raw, 1.0f), 130.0f);
    float Nf = (float)N;
    int   sh = (int)rintf(shf);

    __shared__ float rw[OC_N][2][KW];

    {
        int oc = t >> 1, ch = t & 1;
        const float* w = bw + (oc * 2 + ch) * KW;
        float KdivN = 65.0f / Nf;
        float NdivK = Nf / 65.0f;
        for (int i = 0; i < KW; ++i) {
            float c2  = fmaxf(((float)i + 0.5f) * NdivK - 0.5f, 0.0f);
            float j0f = floorf(c2);
            int   j0  = (int)j0f;
            int   j1  = min(j0 + 1, N - 1);
            float w2  = c2 - j0f;
            float v0, v1;
            {
                float c   = fmaxf(((float)j0 + 0.5f) * KdivN - 0.5f, 0.0f);
                float i0f = floorf(c);
                int   i0  = min((int)i0f, KW - 1);
                int   i1  = min(i0 + 1, KW - 1);
                float w1  = c - i0f;
                v0 = (1.0f - w1) * w[i0] + w1 * w[i1];
            }
            {
                float c   = fmaxf(((float)j1 + 0.5f) * KdivN - 0.5f, 0.0f);
                float i0f = floorf(c);
                int   i0  = min((int)i0f, KW - 1);
                int   i1  = min(i0 + 1, KW - 1);
                float w1  = c - i0f;
                v1 = (1.0f - w1) * w[i0] + w1 * w[i1];
            }
            rw[oc][ch][i] = (1.0f - w2) * v0 + w2 * v1;
        }
    }
    __syncthreads();
    if (t < OC_N) {
        int oc = t;
        unsigned short* ob = wpk + ((size_t)b * OC_N + oc) * KPAD;
        for (int kk = KW; kk < SEC; ++kk) { ob[kk] = 0; ob[SEC + kk] = 0; }
        for (int k = 0; k < KW; ++k) {
            float n  = (float)k;
            float tt = n / FS;
            float phi = 2.0f * PI * f0 * n / FS + PI * chirp * tt * tt;
            float cph = cosf(phi), sph = sinf(phi);
            float I = rw[oc][0][k], Q = rw[oc][1][k];
            float Ip = (I * cph - Q * sph) * gain;
            float Qp = (I * sph + Q * cph) * gain;
            int kk = ((k + sh) % KW + KW) % KW;   // out[(k+sh)%KW] = in[k]
            ob[kk]       = f2bf(Ip);
            ob[SEC + kk] = f2bf(Qp);
        }
    }
}

// ---------------- Kernel B: implicit-GEMM conv via bf16 MFMA -----------------
// block: 4 waves; wave w owns ocs [16w,16w+16); all waves share l-tile of 128.
// MFMA 16x16x32: A row = lane&15 (oc), B col = lane&15 (l stride 8),
// k = 32s + 8*(lane>>4) + e. D: col = lane&15, row = 4*(lane>>4)+reg.
__global__ __launch_bounds__(256) void steer_conv_mfma(
        const float* __restrict__ x, const unsigned short* __restrict__ wpk,
        float* __restrict__ y) {
    int b   = blockIdx.y;
    int l0  = blockIdx.x * LT;
    int tid = threadIdx.x;
    int wv = tid >> 6, lane = tid & 63;
    int c = lane & 15, g = lane >> 4;

    __shared__ __align__(16) unsigned short xt[8][2][XW];  // 6656 B

    const float* xb = x + (size_t)b * 2 * L_LEN;
    // stage 8 phase-shifted bf16 copies: xt[p][ch][i] = x[b][ch][l0-32+i+p]
    #pragma unroll
    for (int it = 0; it < 13; ++it) {           // 13*256 = 8*2*208
        int idx = it * 256 + tid;
        int p  = idx / (2 * XW);
        int r  = idx % (2 * XW);
        int ch = r / XW;
        int i  = r % XW;
        int gi = l0 - 32 + i + p;
        float v = (gi >= 0 && gi < L_LEN) ? xb[(size_t)ch * L_LEN + gi] : 0.0f;
        xt[p][ch][i] = f2bf(v);
    }
    __syncthreads();

    // A fragments (weights) preloaded into registers, 5 K-steps
    const unsigned short* wb = wpk + ((size_t)b * OC_N + wv * 16 + c) * KPAD;
    short8 afr[5];
    #pragma unroll
    for (int s = 0; s < 5; ++s)
        afr[s] = *(const short8*)(wb + 32 * s + 8 * g);

    // per-lane B-fragment element offsets within xt[p]
    int boff[5];
    #pragma unroll
    for (int s = 0; s < 5; ++s) {
        int kk0 = 32 * s + 8 * g;
        int ch  = (kk0 >= SEC) ? 1 : 0;
        int t0  = kk0 - SEC * ch;
        boff[s] = ch * XW + 8 * c + t0;          // *2B is 16-byte aligned
    }

    f32x4 acc[8];
    #pragma unroll
    for (int p = 0; p < 8; ++p) acc[p] = (f32x4){0.f, 0.f, 0.f, 0.f};

    #pragma unroll
    for (int p = 0; p < 8; ++p) {
        const unsigned short* xp = &xt[p][0][0];
        #pragma unroll
        for (int s = 0; s < 5; ++s) {
            short8 bfr = *(const short8*)(xp + boff[s]);
            acc[p] = __builtin_amdgcn_mfma_f32_16x16x32_bf16(afr[s], bfr, acc[p], 0, 0, 0);
        }
    }

    // store: lane holds, per row r, 8 contiguous l = l0+8c+p (p=0..7)
    #pragma unroll
    for (int r = 0; r < 4; ++r) {
        int oc = wv * 16 + 4 * g + r;
        float* yr = y + ((size_t)b * OC_N + oc) * L_LEN + l0 + 8 * c;
        f32x4 lo = { acc[0][r], acc[1][r], acc[2][r], acc[3][r] };
        f32x4 hi = { acc[4][r], acc[5][r], acc[6][r], acc[7][r] };
        *(f32x4*)yr       = lo;
        *((f32x4*)yr + 1) = hi;
    }
}

extern "C" void kernel_launch(void* const* d_in, const int* in_sizes, int n_in,
                              void* d_out, int out_size, void* d_ws, size_t ws_size,
                              hipStream_t stream) {
    const float* x  = (const float*)d_in[0];
    const int*   z  = (const int*)d_in[1];
    const float* s  = (const float*)d_in[2];
    const float* bw = (const float*)d_in[3];
    float* y = (float*)d_out;
    unsigned short* wpk = (unsigned short*)d_ws;   // 32*64*160*2 = 655 KB

    steer_weights<<<dim3(B_N), dim3(128), 0, stream>>>(z, s, bw, wpk);
    steer_conv_mfma<<<dim3(L_LEN / LT, B_N), dim3(256), 0, stream>>>(x, wpk, y);
}

// Round 3
// 147.266 us; speedup vs baseline: 3.0337x; 1.4178x over previous
//
#include <hip/hip_runtime.h>
#include <math.h>

#define KW 65
#define L_LEN 65536
#define B_N 32
#define OC_N 64
#define KPAD 160      // two 80-wide channel sections
#define SEC 80
#define LT 256        // l per block
#define XBASE 344     // base (phase-0) window length in shorts, mult of 8

typedef __attribute__((ext_vector_type(8))) short short8;
typedef __attribute__((ext_vector_type(4))) float f32x4;

__device__ __forceinline__ unsigned short f2bf(float f) {
    unsigned u = __builtin_bit_cast(unsigned, f);
    unsigned r = u + 0x7FFFu + ((u >> 16) & 1u);
    return (unsigned short)(r >> 16);
}

__device__ __forceinline__ float nan0(float v) {
    if (isnan(v)) return 0.0f;
    if (isinf(v)) return v > 0.0f ? 3.4028234663852886e38f : -3.4028234663852886e38f;
    return v;
}

// ---------------- Kernel A: steered weights, packed bf16 [B][OC][160] -------
__global__ __launch_bounds__(256) void steer_weights(
        const int* __restrict__ z, const float* __restrict__ s,
        const float* __restrict__ bw, unsigned short* __restrict__ wpk) {
    const float PI = 3.14159265358979323846f;
    const float FS = 50000000.0f;
    int b = blockIdx.x;
    int t = threadIdx.x;

    const int*   zb = z + b * 5;
    const float* sb = s + b * 5;
    float f0    = (zb[0] > 0) ? nan0(sb[0]) : 0.0f;
    float alpha = (zb[1] > 0) ? nan0(sb[1]) : 1.0f;
    float gain  = (zb[2] > 0) ? nan0(sb[2]) : 1.0f;
    float shf   = (zb[3] > 0) ? nan0(sb[3]) : 0.0f;
    float chirp = (zb[4] > 0) ? nan0(sb[4]) : 0.0f;

    float a = fmaxf(alpha, 0.001f);
    float Nf_raw = rintf(65.0f / a);          // jnp.round = half-to-even
    int   N  = (int)fminf(fmaxf(Nf_raw, 1.0f), 130.0f);
    float Nf = (float)N;
    int   sh = (int)rintf(shf);

    __shared__ float rw[OC_N][2][KW];
    __shared__ float cph[KW], sph[KW];

    // phi table (waves 0): 65 sincos in parallel
    if (t < KW) {
        float n  = (float)t;
        float tt = n / FS;
        float phi = 2.0f * PI * f0 * n / FS + PI * chirp * tt * tt;
        cph[t] = cosf(phi);
        sph[t] = sinf(phi);
    }
    // resample (waves 2,3): one (oc,ch) row each
    if (t >= 128) {
        int oc = (t - 128) >> 1, ch = t & 1;
        const float* w = bw + (oc * 2 + ch) * KW;
        float KdivN = 65.0f / Nf;
        float NdivK = Nf / 65.0f;
        for (int i = 0; i < KW; ++i) {
            float c2  = fmaxf(((float)i + 0.5f) * NdivK - 0.5f, 0.0f);
            float j0f = floorf(c2);
            int   j0  = (int)j0f;
            int   j1  = min(j0 + 1, N - 1);
            float w2  = c2 - j0f;
            float v0, v1;
            {
                float c   = fmaxf(((float)j0 + 0.5f) * KdivN - 0.5f, 0.0f);
                float i0f = floorf(c);
                int   i0  = min((int)i0f, KW - 1);
                int   i1  = min(i0 + 1, KW - 1);
                float w1  = c - i0f;
                v0 = (1.0f - w1) * w[i0] + w1 * w[i1];
            }
            {
                float c   = fmaxf(((float)j1 + 0.5f) * KdivN - 0.5f, 0.0f);
                float i0f = floorf(c);
                int   i0  = min((int)i0f, KW - 1);
                int   i1  = min(i0 + 1, KW - 1);
                float w1  = c - i0f;
                v1 = (1.0f - w1) * w[i0] + w1 * w[i1];
            }
            rw[oc][ch][i] = (1.0f - w2) * v0 + w2 * v1;
        }
    }
    __syncthreads();
    // mix + gain + shift + pack: 4 threads per oc
    {
        int oc = t >> 2, q = t & 3;
        unsigned short* ob = wpk + ((size_t)b * OC_N + oc) * KPAD;
        int sh0 = ((sh % KW) + KW) % KW;
        int k0 = 17 * q, k1 = min(KW, k0 + 17);
        for (int k = k0; k < k1; ++k) {
            float I = rw[oc][0][k], Q = rw[oc][1][k];
            float cp = cph[k], sp = sph[k];
            float Ip = (I * cp - Q * sp) * gain;
            float Qp = (I * sp + Q * cp) * gain;
            int kk = k + sh0; if (kk >= KW) kk -= KW;
            ob[kk]       = f2bf(Ip);
            ob[SEC + kk] = f2bf(Qp);
        }
        if (q == 3) {
            for (int kk = KW; kk < SEC; ++kk) { ob[kk] = 0; ob[SEC + kk] = 0; }
        }
    }
}

// ---------------- Kernel B: implicit-GEMM conv via bf16 MFMA -----------------
// Block tile: 64 oc x 256 l. 4 waves: wave w -> oc half a=w&1 (2 oc-tiles of 16),
// l-subtile lsub=w>>1 (128 l). MFMA 16x16x32: col c -> l = l0+128*lsub+8c+p.
// 8 phase-shifted bf16 x-copies in LDS, built from one staged base copy.
__global__ __launch_bounds__(256, 3) void steer_conv_mfma(
        const float* __restrict__ x, const unsigned short* __restrict__ wpk,
        float* __restrict__ y) {
    int b   = blockIdx.y;
    int l0  = blockIdx.x * LT;
    int tid = threadIdx.x;
    int wv = tid >> 6, lane = tid & 63;
    int c = lane & 15, g = lane >> 4;
    int a = wv & 1, lsub = wv >> 1;

    __shared__ __align__(16) unsigned short xt[8][2][XBASE];  // 11 KB

    // A fragments (weights) from global (L2-resident), independent of LDS
    short8 afr[2][5];
    #pragma unroll
    for (int ot = 0; ot < 2; ++ot) {
        const unsigned short* wb = wpk + ((size_t)b * OC_N + 32 * a + 16 * ot + c) * KPAD;
        #pragma unroll
        for (int s = 0; s < 5; ++s)
            afr[ot][s] = *(const short8*)(wb + 32 * s + 8 * g);
    }

    const float* xb = x + (size_t)b * 2 * L_LEN;

    // step 1: stage base copy (phase 0), coalesced float4 -> bf16
    if (tid < 172) {
        int ch = tid / 86, i4 = tid % 86;
        int gi = l0 - 32 + 4 * i4;
        float4 v;
        if (gi >= 0 && gi + 3 < L_LEN) {
            v = *(const float4*)(xb + (size_t)ch * L_LEN + gi);
        } else {
            float tmp[4];
            #pragma unroll
            for (int u = 0; u < 4; ++u) {
                int q = gi + u;
                tmp[u] = (q >= 0 && q < L_LEN) ? xb[(size_t)ch * L_LEN + q] : 0.0f;
            }
            v = make_float4(tmp[0], tmp[1], tmp[2], tmp[3]);
        }
        unsigned r0 = (unsigned)f2bf(v.x) | ((unsigned)f2bf(v.y) << 16);
        unsigned r1 = (unsigned)f2bf(v.z) | ((unsigned)f2bf(v.w) << 16);
        *(uint2*)&xt[0][ch][4 * i4] = make_uint2(r0, r1);
    }
    __syncthreads();

    // step 2: build phases 1..7 by 16-bit funnel shifts of the base copy
    if (tid < 84) {
        int ch = tid / 42, j = tid % 42;
        const unsigned* src = (const unsigned*)&xt[0][ch][8 * j];
        unsigned d[8];
        #pragma unroll
        for (int i = 0; i < 8; ++i) d[i] = src[i];
        #pragma unroll
        for (int p = 1; p < 8; ++p) {
            int q = p >> 1;
            unsigned o[4];
            #pragma unroll
            for (int i = 0; i < 4; ++i)
                o[i] = (p & 1) ? ((d[i + q] >> 16) | (d[i + q + 1] << 16)) : d[i + q];
            *(uint4*)&xt[p][ch][8 * j] = make_uint4(o[0], o[1], o[2], o[3]);
        }
    }

    // per-lane B-fragment element offsets (shorts) within a phase copy
    int boff[5];
    #pragma unroll
    for (int s = 0; s < 5; ++s) {
        int k0 = 32 * s + 8 * g;
        int ch = (k0 >= SEC) ? 1 : 0;
        int t0 = k0 - SEC * ch;
        boff[s] = ch * XBASE + 128 * lsub + 8 * c + t0;   // *2B -> 16B aligned
    }
    __syncthreads();

    f32x4 acc[2][8];
    #pragma unroll
    for (int ot = 0; ot < 2; ++ot)
        #pragma unroll
        for (int p = 0; p < 8; ++p) acc[ot][p] = (f32x4){0.f, 0.f, 0.f, 0.f};

    #pragma unroll
    for (int p = 0; p < 8; ++p) {
        const unsigned short* xp = &xt[p][0][0];
        #pragma unroll
        for (int s = 0; s < 5; ++s) {
            short8 bfr = *(const short8*)(xp + boff[s]);
            acc[0][p] = __builtin_amdgcn_mfma_f32_16x16x32_bf16(afr[0][s], bfr, acc[0][p], 0, 0, 0);
            acc[1][p] = __builtin_amdgcn_mfma_f32_16x16x32_bf16(afr[1][s], bfr, acc[1][p], 0, 0, 0);
        }
    }

    // store: lane holds 8 contiguous l per (ot, r): l = l0+128*lsub+8c+p
    #pragma unroll
    for (int ot = 0; ot < 2; ++ot) {
        #pragma unroll
        for (int r = 0; r < 4; ++r) {
            int oc = 32 * a + 16 * ot + 4 * g + r;
            float* yr = y + ((size_t)b * OC_N + oc) * L_LEN + l0 + 128 * lsub + 8 * c;
            f32x4 lo = { acc[ot][0][r], acc[ot][1][r], acc[ot][2][r], acc[ot][3][r] };
            f32x4 hi = { acc[ot][4][r], acc[ot][5][r], acc[ot][6][r], acc[ot][7][r] };
            *(f32x4*)yr       = lo;
            *((f32x4*)yr + 1) = hi;
        }
    }
}

extern "C" void kernel_launch(void* const* d_in, const int* in_sizes, int n_in,
                              void* d_out, int out_size, void* d_ws, size_t ws_size,
                              hipStream_t stream) {
    const float* x  = (const float*)d_in[0];
    const int*   z  = (const int*)d_in[1];
    const float* s  = (const float*)d_in[2];
    const float* bw = (const float*)d_in[3];
    float* y = (float*)d_out;
    unsigned short* wpk = (unsigned short*)d_ws;   // 32*64*160*2 = 655 KB

    steer_weights<<<dim3(B_N), dim3(256), 0, stream>>>(z, s, bw, wpk);
    steer_conv_mfma<<<dim3(L_LEN / LT, B_N), dim3(256), 0, stream>>>(x, wpk, y);
}

// Round 4
// 142.164 us; speedup vs baseline: 3.1426x; 1.0359x over previous
//
#include <hip/hip_runtime.h>
#include <math.h>

#define KW 65
#define L_LEN 65536
#define B_N 32
#define OC_N 64
#define KPAD 160      // two 80-wide channel sections
#define SEC 80
#define LT 256        // l per tile
#define NT 4          // tiles per block
#define LGRP (LT*NT)  // 1024 l per block
#define XBASE 344     // base (phase-0) window length in shorts, mult of 8

typedef __attribute__((ext_vector_type(8))) short short8;
typedef __attribute__((ext_vector_type(4))) float f32x4;

__device__ __forceinline__ unsigned short f2bf(float f) {
    unsigned u = __builtin_bit_cast(unsigned, f);
    unsigned r = u + 0x7FFFu + ((u >> 16) & 1u);
    return (unsigned short)(r >> 16);
}

__device__ __forceinline__ float nan0(float v) {
    if (isnan(v)) return 0.0f;
    if (isinf(v)) return v > 0.0f ? 3.4028234663852886e38f : -3.4028234663852886e38f;
    return v;
}

// ---------------- Kernel A: steered weights, packed bf16 [B][OC][160] -------
__global__ __launch_bounds__(256) void steer_weights(
        const int* __restrict__ z, const float* __restrict__ s,
        const float* __restrict__ bw, unsigned short* __restrict__ wpk) {
    const float PI = 3.14159265358979323846f;
    const float FS = 50000000.0f;
    int b = blockIdx.x;
    int t = threadIdx.x;

    const int*   zb = z + b * 5;
    const float* sb = s + b * 5;
    float f0    = (zb[0] > 0) ? nan0(sb[0]) : 0.0f;
    float alpha = (zb[1] > 0) ? nan0(sb[1]) : 1.0f;
    float gain  = (zb[2] > 0) ? nan0(sb[2]) : 1.0f;
    float shf   = (zb[3] > 0) ? nan0(sb[3]) : 0.0f;
    float chirp = (zb[4] > 0) ? nan0(sb[4]) : 0.0f;

    float a = fmaxf(alpha, 0.001f);
    float Nf_raw = rintf(65.0f / a);          // jnp.round = half-to-even
    int   N  = (int)fminf(fmaxf(Nf_raw, 1.0f), 130.0f);
    float Nf = (float)N;
    int   sh = (int)rintf(shf);

    __shared__ float rw[OC_N][2][KW];
    __shared__ float cph[KW], sph[KW];
    __shared__ int   j0t[KW], j1t[KW];
    __shared__ float w2t[KW];
    __shared__ int   i0t[130], i1t[130];
    __shared__ float w1t[130];

    // coefficient tables (depend only on N) + phase table, all in parallel
    if (t < KW) {
        float n  = (float)t;
        float tt = n / FS;
        float phi = 2.0f * PI * f0 * n / FS + PI * chirp * tt * tt;
        cph[t] = cosf(phi);
        sph[t] = sinf(phi);
        float c2  = fmaxf(((float)t + 0.5f) * (Nf / 65.0f) - 0.5f, 0.0f);
        float j0f = floorf(c2);
        j0t[t] = (int)j0f;
        j1t[t] = min((int)j0f + 1, N - 1);
        w2t[t] = c2 - j0f;
    } else if (t < KW + 130) {
        int j = t - KW;
        float c   = fmaxf(((float)j + 0.5f) * (65.0f / Nf) - 0.5f, 0.0f);
        float i0f = floorf(c);
        int   i0  = min((int)i0f, KW - 1);
        i0t[j] = i0;
        i1t[j] = min(i0 + 1, KW - 1);
        w1t[j] = c - i0f;
    }
    __syncthreads();

    // resample: 128 rows x 65 taps as table-lookup lerps
    for (int item = t; item < 128 * KW; item += 256) {
        int row = item / KW, i = item % KW;     // row = oc*2 + ch
        const float* w = bw + row * KW;
        int j0 = j0t[i], j1 = j1t[i];
        float v0 = (1.0f - w1t[j0]) * w[i0t[j0]] + w1t[j0] * w[i1t[j0]];
        float v1 = (1.0f - w1t[j1]) * w[i0t[j1]] + w1t[j1] * w[i1t[j1]];
        rw[row >> 1][row & 1][i] = (1.0f - w2t[i]) * v0 + w2t[i] * v1;
    }
    __syncthreads();

    // mix + gain + shift + pack: 4 threads per oc
    {
        int oc = t >> 2, q = t & 3;
        unsigned short* ob = wpk + ((size_t)b * OC_N + oc) * KPAD;
        int sh0 = ((sh % KW) + KW) % KW;
        int k0 = 17 * q, k1 = min(KW, k0 + 17);
        for (int k = k0; k < k1; ++k) {
            float I = rw[oc][0][k], Q = rw[oc][1][k];
            float cp = cph[k], sp = sph[k];
            float Ip = (I * cp - Q * sp) * gain;
            float Qp = (I * sp + Q * cp) * gain;
            int kk = k + sh0; if (kk >= KW) kk -= KW;
            ob[kk]       = f2bf(Ip);
            ob[SEC + kk] = f2bf(Qp);
        }
        if (q == 3) {
            for (int kk = KW; kk < SEC; ++kk) { ob[kk] = 0; ob[SEC + kk] = 0; }
        }
    }
}

// ---------------- Kernel B: implicit-GEMM conv via bf16 MFMA -----------------
// Block: 64 oc x 1024 l (4 tiles of 256), 4 waves (oc-half x l-half per tile).
// Double-buffered LDS of 8 phase-shifted bf16 x-copies; role-split pipeline:
// loaders (tid>=84) write base copy / prefetch next tile while builders
// (tid<84) construct phases 1..7; MFMA+stores overlap in-flight loads.
__global__ __launch_bounds__(256, 3) void steer_conv_mfma(
        const float* __restrict__ x, const unsigned short* __restrict__ wpk,
        float* __restrict__ y) {
    int b   = blockIdx.y;
    int L0  = blockIdx.x * LGRP;
    int tid = threadIdx.x;
    int wv = tid >> 6, lane = tid & 63;
    int c = lane & 15, g = lane >> 4;
    int a = wv & 1, lsub = wv >> 1;

    __shared__ __align__(16) unsigned short xt[2][8][2][XBASE];  // 22 KB

    // A fragments (weights) loaded once per block
    short8 afr[2][5];
    #pragma unroll
    for (int ot = 0; ot < 2; ++ot) {
        const unsigned short* wb = wpk + ((size_t)b * OC_N + 32 * a + 16 * ot + c) * KPAD;
        #pragma unroll
        for (int s = 0; s < 5; ++s)
            afr[ot][s] = *(const short8*)(wb + 32 * s + 8 * g);
    }

    const float* xb = x + (size_t)b * 2 * L_LEN;

    bool isLoader = (tid >= 84);
    int lidx = tid - 84;
    int lch = lidx / 86, li4 = lidx % 86;

    // per-lane B-fragment element offsets (shorts) within a phase copy
    int boff[5];
    #pragma unroll
    for (int s = 0; s < 5; ++s) {
        int k0 = 32 * s + 8 * g;
        int ch = (k0 >= SEC) ? 1 : 0;
        int t0 = k0 - SEC * ch;
        boff[s] = ch * XBASE + 128 * lsub + 8 * c + t0;   // *2B -> 16B aligned
    }

    float4 v;
    if (isLoader) {
        int gi = L0 - 32 + 4 * li4;
        if (gi >= 0 && gi + 3 < L_LEN) {
            v = *(const float4*)(xb + (size_t)lch * L_LEN + gi);
        } else {
            float tmp[4];
            #pragma unroll
            for (int u = 0; u < 4; ++u) {
                int q = gi + u;
                tmp[u] = (q >= 0 && q < L_LEN) ? xb[(size_t)lch * L_LEN + q] : 0.0f;
            }
            v = make_float4(tmp[0], tmp[1], tmp[2], tmp[3]);
        }
    }

    int cur = 0;
    for (int t = 0; t < NT; ++t) {
        int l0 = L0 + t * LT;
        // write bf16 base copy (phase 0) of tile t
        if (isLoader) {
            unsigned r0 = (unsigned)f2bf(v.x) | ((unsigned)f2bf(v.y) << 16);
            unsigned r1 = (unsigned)f2bf(v.z) | ((unsigned)f2bf(v.w) << 16);
            *(uint2*)&xt[cur][0][lch][4 * li4] = make_uint2(r0, r1);
        }
        __syncthreads();
        if (tid < 84) {
            // build phases 1..7 by 16-bit funnel shifts of the base copy
            int ch = tid / 42, j = tid % 42;
            const unsigned* src = (const unsigned*)&xt[cur][0][ch][8 * j];
            unsigned d[8];
            #pragma unroll
            for (int i = 0; i < 8; ++i) d[i] = src[i];
            #pragma unroll
            for (int p = 1; p < 8; ++p) {
                int q = p >> 1;
                unsigned o[4];
                #pragma unroll
                for (int i = 0; i < 4; ++i)
                    o[i] = (p & 1) ? ((d[i + q] >> 16) | (d[i + q + 1] << 16)) : d[i + q];
                *(uint4*)&xt[cur][p][ch][8 * j] = make_uint4(o[0], o[1], o[2], o[3]);
            }
        } else if (t + 1 < NT) {
            // prefetch next tile's window into registers
            int gi = L0 + (t + 1) * LT - 32 + 4 * li4;
            if (gi >= 0 && gi + 3 < L_LEN) {
                v = *(const float4*)(xb + (size_t)lch * L_LEN + gi);
            } else {
                float tmp[4];
                #pragma unroll
                for (int u = 0; u < 4; ++u) {
                    int q = gi + u;
                    tmp[u] = (q >= 0 && q < L_LEN) ? xb[(size_t)lch * L_LEN + q] : 0.0f;
                }
                v = make_float4(tmp[0], tmp[1], tmp[2], tmp[3]);
            }
        }
        __syncthreads();

        f32x4 acc[2][8];
        #pragma unroll
        for (int ot = 0; ot < 2; ++ot)
            #pragma unroll
            for (int p = 0; p < 8; ++p) acc[ot][p] = (f32x4){0.f, 0.f, 0.f, 0.f};

        #pragma unroll
        for (int p = 0; p < 8; ++p) {
            const unsigned short* xp = &xt[cur][p][0][0];
            #pragma unroll
            for (int s = 0; s < 5; ++s) {
                short8 bfr = *(const short8*)(xp + boff[s]);
                acc[0][p] = __builtin_amdgcn_mfma_f32_16x16x32_bf16(afr[0][s], bfr, acc[0][p], 0, 0, 0);
                acc[1][p] = __builtin_amdgcn_mfma_f32_16x16x32_bf16(afr[1][s], bfr, acc[1][p], 0, 0, 0);
            }
        }

        // store: lane holds 8 contiguous l per (ot, r): l = l0+128*lsub+8c+p
        #pragma unroll
        for (int ot = 0; ot < 2; ++ot) {
            #pragma unroll
            for (int r = 0; r < 4; ++r) {
                int oc = 32 * a + 16 * ot + 4 * g + r;
                float* yr = y + ((size_t)b * OC_N + oc) * L_LEN + l0 + 128 * lsub + 8 * c;
                f32x4 lo = { acc[ot][0][r], acc[ot][1][r], acc[ot][2][r], acc[ot][3][r] };
                f32x4 hi = { acc[ot][4][r], acc[ot][5][r], acc[ot][6][r], acc[ot][7][r] };
                *(f32x4*)yr       = lo;
                *((f32x4*)yr + 1) = hi;
            }
        }
        cur ^= 1;
    }
}

extern "C" void kernel_launch(void* const* d_in, const int* in_sizes, int n_in,
                              void* d_out, int out_size, void* d_ws, size_t ws_size,
                              hipStream_t stream) {
    const float* x  = (const float*)d_in[0];
    const int*   z  = (const int*)d_in[1];
    const float* s  = (const float*)d_in[2];
    const float* bw = (const float*)d_in[3];
    float* y = (float*)d_out;
    unsigned short* wpk = (unsigned short*)d_ws;   // 32*64*160*2 = 655 KB

    steer_weights<<<dim3(B_N), dim3(256), 0, stream>>>(z, s, bw, wpk);
    steer_conv_mfma<<<dim3(L_LEN / LGRP, B_N), dim3(256), 0, stream>>>(x, wpk, y);
}